// Round 1
// baseline (1614.955 us; speedup 1.0000x reference)
//
#include <hip/hip_runtime.h>
#include <math.h>

#define N_NODES 100000
#define N_EDGES 3200000
#define NCLASS  64
#define TOPK    16
#define NHID    128
#define DEG     6

// ---------- wave helpers (wave64) ----------
__device__ __forceinline__ float wave_max(float v) {
    #pragma unroll
    for (int off = 1; off < 64; off <<= 1) v = fmaxf(v, __shfl_xor(v, off));
    return v;
}
__device__ __forceinline__ float wave_sum(float v) {
    #pragma unroll
    for (int off = 1; off < 64; off <<= 1) v += __shfl_xor(v, off);
    return v;
}

// ---------- CSR build ----------
__global__ void zero_kernel(int* __restrict__ p, int n) {
    int i = blockIdx.x * blockDim.x + threadIdx.x;
    if (i < n) p[i] = 0;
}

__global__ void hist_kernel(const int* __restrict__ erow, int* __restrict__ cnt) {
    int i = blockIdx.x * blockDim.x + threadIdx.x;
    if (i < N_EDGES) atomicAdd(&cnt[erow[i]], 1);
}

#define SCAN_BS    256
#define SCAN_EPT   8
#define SCAN_CHUNK (SCAN_BS * SCAN_EPT)            // 2048
#define SCAN_NBLK  ((N_NODES + SCAN_CHUNK - 1) / SCAN_CHUNK)  // 49

__global__ void scan_phase1(const int* __restrict__ cnt, int* __restrict__ partial) {
    __shared__ int sdata[SCAN_BS];
    int base = blockIdx.x * SCAN_CHUNK + threadIdx.x * SCAN_EPT;
    int s = 0;
    #pragma unroll
    for (int k = 0; k < SCAN_EPT; k++) {
        int idx = base + k;
        if (idx < N_NODES) s += cnt[idx];
    }
    sdata[threadIdx.x] = s;
    __syncthreads();
    for (int off = SCAN_BS / 2; off > 0; off >>= 1) {
        if (threadIdx.x < off) sdata[threadIdx.x] += sdata[threadIdx.x + off];
        __syncthreads();
    }
    if (threadIdx.x == 0) partial[blockIdx.x] = sdata[0];
}

__global__ void scan_phase2(int* __restrict__ partial, int* __restrict__ row_ptr) {
    if (threadIdx.x == 0 && blockIdx.x == 0) {
        int acc = 0;
        for (int b = 0; b < SCAN_NBLK; b++) {
            int v = partial[b]; partial[b] = acc; acc += v;
        }
        row_ptr[N_NODES] = acc;   // == N_EDGES
    }
}

__global__ void scan_phase3(const int* __restrict__ cnt, const int* __restrict__ partial,
                            int* __restrict__ row_ptr, int* __restrict__ nxt) {
    __shared__ int sdata[SCAN_BS];
    int tid  = threadIdx.x;
    int base = blockIdx.x * SCAN_CHUNK + tid * SCAN_EPT;
    int loc[SCAN_EPT];
    int s = 0;
    #pragma unroll
    for (int k = 0; k < SCAN_EPT; k++) {
        int idx = base + k;
        int v = (idx < N_NODES) ? cnt[idx] : 0;
        loc[k] = s;
        s += v;
    }
    sdata[tid] = s;
    __syncthreads();
    for (int off = 1; off < SCAN_BS; off <<= 1) {
        int v = 0;
        if (tid >= off) v = sdata[tid - off];
        __syncthreads();
        if (tid >= off) sdata[tid] += v;
        __syncthreads();
    }
    int thread_excl = ((tid > 0) ? sdata[tid - 1] : 0) + partial[blockIdx.x];
    #pragma unroll
    for (int k = 0; k < SCAN_EPT; k++) {
        int idx = base + k;
        if (idx < N_NODES) {
            int v = thread_excl + loc[k];
            row_ptr[idx] = v;
            nxt[idx]     = v;
        }
    }
}

__global__ void scatter_kernel(const int* __restrict__ erow, const int* __restrict__ ecol,
                               const float* __restrict__ eval, int* __restrict__ nxt,
                               int* __restrict__ cols_s, float* __restrict__ vals_s) {
    int i = blockIdx.x * blockDim.x + threadIdx.x;
    if (i < N_EDGES) {
        int r   = erow[i];
        int pos = atomicAdd(&nxt[r], 1);
        cols_s[pos] = ecol[i];
        vals_s[pos] = eval[i];
    }
}

// ---------- gating: softmax64 -> top16 -> MLP -> softmax6 ----------
__global__ __launch_bounds__(256) void gating_kernel(
        const float* __restrict__ x,  const float* __restrict__ W1,
        const float* __restrict__ b1, const float* __restrict__ W2,
        const float* __restrict__ b2, float* __restrict__ weight,
        float* __restrict__ out_acc) {
    __shared__ float sW1t[TOPK * NHID];   // transposed: [k][j] — conflict-free reads
    __shared__ float sb1[NHID];
    __shared__ float sW2[DEG * NHID];
    __shared__ float sb2[DEG];
    int tid = threadIdx.x;
    for (int idx = tid; idx < NHID * TOPK; idx += 256) {
        int k = idx / NHID, j = idx - k * NHID;
        sW1t[idx] = W1[j * TOPK + k];
    }
    for (int i = tid; i < NHID; i += 256) sb1[i] = b1[i];
    for (int i = tid; i < DEG * NHID; i += 256) sW2[i] = W2[i];
    if (tid < DEG) sb2[tid] = b2[tid];
    __syncthreads();

    int wave = tid >> 6;
    int lane = tid & 63;
    int node = blockIdx.x * 4 + wave;
    if (node >= N_NODES) return;

    float v = x[node * NCLASS + lane];
    float m = wave_max(v);
    float e = __expf(v - m);
    float s = wave_sum(e);
    float p = e / s;

    // top-16 descending (wave-uniform after each reduction)
    float tk[TOPK];
    float cur = p;
    #pragma unroll
    for (int k = 0; k < TOPK; k++) {
        float mk = wave_max(cur);
        tk[k] = mk;
        unsigned long long mask = __ballot(cur == mk);
        int first = __ffsll(mask) - 1;
        if (lane == first) cur = -1.0f;   // p >= 0, so -1 acts as -inf
    }

    // layer 1: lane computes h[lane] and h[lane+64]
    float h0 = sb1[lane], h1 = sb1[lane + 64];
    #pragma unroll
    for (int k = 0; k < TOPK; k++) {
        h0 += tk[k] * sW1t[k * NHID + lane];
        h1 += tk[k] * sW1t[k * NHID + lane + 64];
    }
    h0 = (h0 > 0.f) ? h0 : 0.1f * h0;
    h1 = (h1 > 0.f) ? h1 : 0.1f * h1;

    // layer 2 + softmax over 6 hop-logits
    float w[DEG];
    float wm = -1e30f;
    #pragma unroll
    for (int d = 0; d < DEG; d++) {
        float part = h0 * sW2[d * NHID + lane] + h1 * sW2[d * NHID + lane + 64];
        w[d] = wave_sum(part) + sb2[d];
        wm = fmaxf(wm, w[d]);
    }
    float wsum = 0.f;
    #pragma unroll
    for (int d = 0; d < DEG; d++) { w[d] = __expf(w[d] - wm); wsum += w[d]; }
    float inv = 1.0f / wsum;

    if (lane < DEG) weight[node * DEG + lane] = w[lane] * inv;
    out_acc[node * NCLASS + lane] = w[0] * inv * v;   // hop-0 term uses raw x
}

// ---------- SPMM hop: one wave per row, lane = channel ----------
__global__ __launch_bounds__(256) void spmm_kernel(
        const float* __restrict__ src, float* __restrict__ dst,
        const int* __restrict__ row_ptr, const int* __restrict__ cols_s,
        const float* __restrict__ vals_s, const float* __restrict__ weight,
        float* __restrict__ out_acc, float* __restrict__ final_out,
        int hop, int is_last) {
    int wave = threadIdx.x >> 6;
    int lane = threadIdx.x & 63;
    int node = blockIdx.x * 4 + wave;
    if (node >= N_NODES) return;

    int start = row_ptr[node], end = row_ptr[node + 1];
    float acc = 0.f;
    for (int base = start; base < end; base += 64) {
        int e = base + lane;
        int cl = 0; float vl = 0.f;
        if (e < end) { cl = cols_s[e]; vl = vals_s[e]; }
        int cnt = min(64, end - base);
        for (int j = 0; j < cnt; j++) {
            int   col = __shfl(cl, j);
            float val = __shfl(vl, j);
            acc += val * src[col * NCLASS + lane];
        }
    }

    float w = weight[node * DEG + hop];
    if (!is_last) {
        dst[node * NCLASS + lane] = acc;
        out_acc[node * NCLASS + lane] += w * acc;
    } else {
        float v = out_acc[node * NCLASS + lane] + w * acc;
        float m = wave_max(v);
        float e2 = __expf(v - m);
        float s = wave_sum(e2);
        final_out[node * NCLASS + lane] = v - m - __logf(s);
    }
}

extern "C" void kernel_launch(void* const* d_in, const int* in_sizes, int n_in,
                              void* d_out, int out_size, void* d_ws, size_t ws_size,
                              hipStream_t stream) {
    const float* x    = (const float*)d_in[0];
    const int*   erow = (const int*)  d_in[1];
    const int*   ecol = (const int*)  d_in[2];
    const float* eval = (const float*)d_in[3];
    const float* W1   = (const float*)d_in[4];
    const float* b1   = (const float*)d_in[5];
    const float* W2   = (const float*)d_in[6];
    const float* b2   = (const float*)d_in[7];
    float* out = (float*)d_out;   // also the hop-accumulation buffer

    char* ws = (char*)d_ws;
    size_t off = 0;
    auto alloc = [&](size_t bytes) -> void* {
        void* p = ws + off;
        off = (off + bytes + 255) & ~(size_t)255;
        return p;
    };
    int*   cnt     = (int*)  alloc((size_t)N_NODES * 4);
    int*   row_ptr = (int*)  alloc((size_t)(N_NODES + 1) * 4);
    int*   nxt     = (int*)  alloc((size_t)N_NODES * 4);
    int*   partial = (int*)  alloc(256 * 4);
    int*   cols_s  = (int*)  alloc((size_t)N_EDGES * 4);
    float* vals_s  = (float*)alloc((size_t)N_EDGES * 4);
    float* cur0    = (float*)alloc((size_t)N_NODES * NCLASS * 4);
    float* cur1    = (float*)alloc((size_t)N_NODES * NCLASS * 4);
    float* weight  = (float*)alloc((size_t)N_NODES * DEG * 4);

    const int EB = (N_EDGES + 255) / 256;          // 12500
    const int NB = (N_NODES + 255) / 256;          // 391
    const int WB = (N_NODES + 3) / 4;              // 25000 (4 waves/block)

    // CSR build
    zero_kernel<<<NB, 256, 0, stream>>>(cnt, N_NODES);
    hist_kernel<<<EB, 256, 0, stream>>>(erow, cnt);
    scan_phase1<<<SCAN_NBLK, SCAN_BS, 0, stream>>>(cnt, partial);
    scan_phase2<<<1, 64, 0, stream>>>(partial, row_ptr);
    scan_phase3<<<SCAN_NBLK, SCAN_BS, 0, stream>>>(cnt, partial, row_ptr, nxt);
    scatter_kernel<<<EB, 256, 0, stream>>>(erow, ecol, eval, nxt, cols_s, vals_s);

    // gating: weights + out = w0 * x
    gating_kernel<<<WB, 256, 0, stream>>>(x, W1, b1, W2, b2, weight, out);

    // 5 hops, out accumulated in d_out; last hop fuses log_softmax
    spmm_kernel<<<WB, 256, 0, stream>>>(x,    cur0, row_ptr, cols_s, vals_s, weight, out, out, 1, 0);
    spmm_kernel<<<WB, 256, 0, stream>>>(cur0, cur1, row_ptr, cols_s, vals_s, weight, out, out, 2, 0);
    spmm_kernel<<<WB, 256, 0, stream>>>(cur1, cur0, row_ptr, cols_s, vals_s, weight, out, out, 3, 0);
    spmm_kernel<<<WB, 256, 0, stream>>>(cur0, cur1, row_ptr, cols_s, vals_s, weight, out, out, 4, 0);
    spmm_kernel<<<WB, 256, 0, stream>>>(cur1, cur0, row_ptr, cols_s, vals_s, weight, out, out, 5, 1);
}

// Round 2
// 1515.152 us; speedup vs baseline: 1.0659x; 1.0659x over previous
//
#include <hip/hip_runtime.h>
#include <math.h>

#define N_NODES 100000
#define N_EDGES 3200000
#define NCLASS  64
#define TOPK    16
#define NHID    128
#define DEG     6

// ---------- bf16 helpers ----------
__device__ __forceinline__ float bf2f(unsigned short u) {
    return __uint_as_float(((unsigned)u) << 16);
}
__device__ __forceinline__ unsigned short f2bf(float f) {
    unsigned u = __float_as_uint(f);
    u = (u + 0x7FFFu + ((u >> 16) & 1u)) >> 16;   // round-to-nearest-even
    return (unsigned short)u;
}

// ---------- wave helpers (wave64) ----------
__device__ __forceinline__ float wave_max(float v) {
    #pragma unroll
    for (int off = 1; off < 64; off <<= 1) v = fmaxf(v, __shfl_xor(v, off));
    return v;
}
__device__ __forceinline__ float wave_sum(float v) {
    #pragma unroll
    for (int off = 1; off < 64; off <<= 1) v += __shfl_xor(v, off);
    return v;
}

// ---------- CSR build ----------
__global__ void hist_kernel(const int* __restrict__ erow, int* __restrict__ cnt) {
    int i = blockIdx.x * blockDim.x + threadIdx.x;
    if (i < N_EDGES) atomicAdd(&cnt[erow[i]], 1);
}

#define SCAN_BS    256
#define SCAN_EPT   8
#define SCAN_CHUNK (SCAN_BS * SCAN_EPT)            // 2048
#define SCAN_NBLK  ((N_NODES + SCAN_CHUNK - 1) / SCAN_CHUNK)  // 49

__global__ void scan_phase1(const int* __restrict__ cnt, int* __restrict__ partial) {
    __shared__ int sdata[SCAN_BS];
    int base = blockIdx.x * SCAN_CHUNK + threadIdx.x * SCAN_EPT;
    int s = 0;
    #pragma unroll
    for (int k = 0; k < SCAN_EPT; k++) {
        int idx = base + k;
        if (idx < N_NODES) s += cnt[idx];
    }
    sdata[threadIdx.x] = s;
    __syncthreads();
    for (int off = SCAN_BS / 2; off > 0; off >>= 1) {
        if (threadIdx.x < off) sdata[threadIdx.x] += sdata[threadIdx.x + off];
        __syncthreads();
    }
    if (threadIdx.x == 0) partial[blockIdx.x] = sdata[0];
}

__global__ void scan_phase2(int* __restrict__ partial, int* __restrict__ row_ptr) {
    if (threadIdx.x == 0 && blockIdx.x == 0) {
        int acc = 0;
        for (int b = 0; b < SCAN_NBLK; b++) {
            int v = partial[b]; partial[b] = acc; acc += v;
        }
        row_ptr[N_NODES] = acc;   // == N_EDGES
    }
}

__global__ void scan_phase3(const int* __restrict__ cnt, const int* __restrict__ partial,
                            int* __restrict__ row_ptr, int* __restrict__ nxt) {
    __shared__ int sdata[SCAN_BS];
    int tid  = threadIdx.x;
    int base = blockIdx.x * SCAN_CHUNK + tid * SCAN_EPT;
    int loc[SCAN_EPT];
    int s = 0;
    #pragma unroll
    for (int k = 0; k < SCAN_EPT; k++) {
        int idx = base + k;
        int v = (idx < N_NODES) ? cnt[idx] : 0;
        loc[k] = s;
        s += v;
    }
    sdata[tid] = s;
    __syncthreads();
    for (int off = 1; off < SCAN_BS; off <<= 1) {
        int v = 0;
        if (tid >= off) v = sdata[tid - off];
        __syncthreads();
        if (tid >= off) sdata[tid] += v;
        __syncthreads();
    }
    int thread_excl = ((tid > 0) ? sdata[tid - 1] : 0) + partial[blockIdx.x];
    #pragma unroll
    for (int k = 0; k < SCAN_EPT; k++) {
        int idx = base + k;
        if (idx < N_NODES) {
            int v = thread_excl + loc[k];
            row_ptr[idx] = v;
            nxt[idx]     = v;
        }
    }
}

// packed (col, val) single 8B store — halves random-write line traffic
__global__ void scatter_kernel(const int* __restrict__ erow, const int* __restrict__ ecol,
                               const float* __restrict__ eval, int* __restrict__ nxt,
                               int2* __restrict__ edges_s) {
    int i = blockIdx.x * blockDim.x + threadIdx.x;
    if (i < N_EDGES) {
        int r   = erow[i];
        int pos = atomicAdd(&nxt[r], 1);
        int2 e;
        e.x = ecol[i];
        e.y = __float_as_int(eval[i]);
        edges_s[pos] = e;
    }
}

// ---------- gating: softmax64 -> top16 -> MLP -> softmax6 (+ bf16 copy of x) ----------
__global__ __launch_bounds__(256) void gating_kernel(
        const float* __restrict__ x,  const float* __restrict__ W1,
        const float* __restrict__ b1, const float* __restrict__ W2,
        const float* __restrict__ b2, float* __restrict__ weight,
        float* __restrict__ out_acc, unsigned short* __restrict__ xbf) {
    __shared__ float sW1t[TOPK * NHID];   // transposed: [k][j]
    __shared__ float sb1[NHID];
    __shared__ float sW2[DEG * NHID];
    __shared__ float sb2[DEG];
    int tid = threadIdx.x;
    for (int idx = tid; idx < NHID * TOPK; idx += 256) {
        int k = idx / NHID, j = idx - k * NHID;
        sW1t[idx] = W1[j * TOPK + k];
    }
    for (int i = tid; i < NHID; i += 256) sb1[i] = b1[i];
    for (int i = tid; i < DEG * NHID; i += 256) sW2[i] = W2[i];
    if (tid < DEG) sb2[tid] = b2[tid];
    __syncthreads();

    int wave = tid >> 6;
    int lane = tid & 63;
    int node = blockIdx.x * 4 + wave;
    if (node >= N_NODES) return;

    float v = x[node * NCLASS + lane];
    xbf[node * NCLASS + lane] = f2bf(v);

    float m = wave_max(v);
    float e = __expf(v - m);
    float s = wave_sum(e);
    float p = e / s;

    // top-16 descending
    float tk[TOPK];
    float cur = p;
    #pragma unroll
    for (int k = 0; k < TOPK; k++) {
        float mk = wave_max(cur);
        tk[k] = mk;
        unsigned long long mask = __ballot(cur == mk);
        int first = __ffsll(mask) - 1;
        if (lane == first) cur = -1.0f;
    }

    float h0 = sb1[lane], h1 = sb1[lane + 64];
    #pragma unroll
    for (int k = 0; k < TOPK; k++) {
        h0 += tk[k] * sW1t[k * NHID + lane];
        h1 += tk[k] * sW1t[k * NHID + lane + 64];
    }
    h0 = (h0 > 0.f) ? h0 : 0.1f * h0;
    h1 = (h1 > 0.f) ? h1 : 0.1f * h1;

    float w[DEG];
    float wm = -1e30f;
    #pragma unroll
    for (int d = 0; d < DEG; d++) {
        float part = h0 * sW2[d * NHID + lane] + h1 * sW2[d * NHID + lane + 64];
        w[d] = wave_sum(part) + sb2[d];
        wm = fmaxf(wm, w[d]);
    }
    float wsum = 0.f;
    #pragma unroll
    for (int d = 0; d < DEG; d++) { w[d] = __expf(w[d] - wm); wsum += w[d]; }
    float inv = 1.0f / wsum;

    if (lane < DEG) weight[node * DEG + lane] = w[lane] * inv;
    out_acc[node * NCLASS + lane] = w[0] * inv * v;
}

// ---------- SPMM hop: one wave per row, lane = channel, bf16 src/dst ----------
__global__ __launch_bounds__(256) void spmm_kernel(
        const unsigned short* __restrict__ src, unsigned short* __restrict__ dst,
        const int* __restrict__ row_ptr, const int2* __restrict__ edges_s,
        const float* __restrict__ weight,
        float* __restrict__ out_acc, float* __restrict__ final_out,
        int hop, int is_last) {
    int wave = threadIdx.x >> 6;
    int lane = threadIdx.x & 63;
    int node = blockIdx.x * 4 + wave;
    if (node >= N_NODES) return;

    int start = row_ptr[node], end = row_ptr[node + 1];
    float acc = 0.f;
    for (int base = start; base < end; base += 64) {
        int e = base + lane;
        int cl = 0; float vl = 0.f;
        if (e < end) {
            int2 pe = edges_s[e];
            cl = pe.x; vl = __int_as_float(pe.y);
        }
        int cnt = min(64, end - base);
        for (int j = 0; j < cnt; j++) {
            int   col = __shfl(cl, j);
            float val = __shfl(vl, j);
            acc += val * bf2f(src[col * NCLASS + lane]);
        }
    }

    float w = weight[node * DEG + hop];
    if (!is_last) {
        dst[node * NCLASS + lane] = f2bf(acc);
        out_acc[node * NCLASS + lane] += w * acc;
    } else {
        float v = out_acc[node * NCLASS + lane] + w * acc;
        float m = wave_max(v);
        float e2 = __expf(v - m);
        float s = wave_sum(e2);
        final_out[node * NCLASS + lane] = v - m - __logf(s);
    }
}

extern "C" void kernel_launch(void* const* d_in, const int* in_sizes, int n_in,
                              void* d_out, int out_size, void* d_ws, size_t ws_size,
                              hipStream_t stream) {
    const float* x    = (const float*)d_in[0];
    const int*   erow = (const int*)  d_in[1];
    const int*   ecol = (const int*)  d_in[2];
    const float* eval = (const float*)d_in[3];
    const float* W1   = (const float*)d_in[4];
    const float* b1   = (const float*)d_in[5];
    const float* W2   = (const float*)d_in[6];
    const float* b2   = (const float*)d_in[7];
    float* out = (float*)d_out;   // also the hop-accumulation buffer

    char* ws = (char*)d_ws;
    size_t off = 0;
    auto alloc = [&](size_t bytes) -> void* {
        void* p = ws + off;
        off = (off + bytes + 255) & ~(size_t)255;
        return p;
    };
    int*   cnt     = (int*)  alloc((size_t)N_NODES * 4);
    int*   row_ptr = (int*)  alloc((size_t)(N_NODES + 1) * 4);
    int*   nxt     = (int*)  alloc((size_t)N_NODES * 4);
    int*   partial = (int*)  alloc(256 * 4);
    int2*  edges_s = (int2*) alloc((size_t)N_EDGES * 8);
    unsigned short* xbf  = (unsigned short*)alloc((size_t)N_NODES * NCLASS * 2);
    unsigned short* cur0 = (unsigned short*)alloc((size_t)N_NODES * NCLASS * 2);
    unsigned short* cur1 = (unsigned short*)alloc((size_t)N_NODES * NCLASS * 2);
    float* weight  = (float*)alloc((size_t)N_NODES * DEG * 4);

    const int EB = (N_EDGES + 255) / 256;          // 12500
    const int WB = (N_NODES + 3) / 4;              // 25000 (4 waves/block)

    // CSR build
    hipMemsetAsync(cnt, 0, (size_t)N_NODES * 4, stream);
    hist_kernel<<<EB, 256, 0, stream>>>(erow, cnt);
    scan_phase1<<<SCAN_NBLK, SCAN_BS, 0, stream>>>(cnt, partial);
    scan_phase2<<<1, 64, 0, stream>>>(partial, row_ptr);
    scan_phase3<<<SCAN_NBLK, SCAN_BS, 0, stream>>>(cnt, partial, row_ptr, nxt);
    scatter_kernel<<<EB, 256, 0, stream>>>(erow, ecol, eval, nxt, edges_s);

    // gating: weights + out = w0 * x, and bf16 copy of x
    gating_kernel<<<WB, 256, 0, stream>>>(x, W1, b1, W2, b2, weight, out, xbf);

    // 5 hops, out accumulated in d_out; last hop fuses log_softmax
    spmm_kernel<<<WB, 256, 0, stream>>>(xbf,  cur0, row_ptr, edges_s, weight, out, out, 1, 0);
    spmm_kernel<<<WB, 256, 0, stream>>>(cur0, cur1, row_ptr, edges_s, weight, out, out, 2, 0);
    spmm_kernel<<<WB, 256, 0, stream>>>(cur1, cur0, row_ptr, edges_s, weight, out, out, 3, 0);
    spmm_kernel<<<WB, 256, 0, stream>>>(cur0, cur1, row_ptr, edges_s, weight, out, out, 4, 0);
    spmm_kernel<<<WB, 256, 0, stream>>>(cur1, cur0, row_ptr, edges_s, weight, out, out, 5, 1);
}

// Round 3
// 1044.368 us; speedup vs baseline: 1.5463x; 1.4508x over previous
//
#include <hip/hip_runtime.h>
#include <math.h>

#define N_NODES 100000
#define N_EDGES 3200000
#define NCLASS  64
#define TOPK    16
#define NHID    128
#define DEG     6

#define NBUCK   391          // ceil(100000/256) buckets of 256 rows
#define NSEG    8            // per-XCD segments per bucket
#define SEGCAP  1280         // capacity per (bucket,segment); mean 1024, sigma 32

// ---------- bf16 helpers ----------
__device__ __forceinline__ float bf2f(unsigned short u) {
    return __uint_as_float(((unsigned)u) << 16);
}
__device__ __forceinline__ unsigned short f2bf(float f) {
    unsigned u = __float_as_uint(f);
    u = (u + 0x7FFFu + ((u >> 16) & 1u)) >> 16;   // round-to-nearest-even
    return (unsigned short)u;
}

// ---------- wave helpers (wave64) ----------
__device__ __forceinline__ float wave_max(float v) {
    #pragma unroll
    for (int off = 1; off < 64; off <<= 1) v = fmaxf(v, __shfl_xor(v, off));
    return v;
}
__device__ __forceinline__ float wave_sum(float v) {
    #pragma unroll
    for (int off = 1; off < 64; off <<= 1) v += __shfl_xor(v, off);
    return v;
}

// ---------- CSR build, phase 1: bucket scatter (XCD-segmented frontiers) ----------
// fill counter for (seg s, bucket b) lives at fill[(s*NBUCK+b)*16]  (64B padded)
__global__ void phase1_bucket(const int* __restrict__ erow, const int* __restrict__ ecol,
                              const float* __restrict__ eval, int* __restrict__ fill,
                              int2* __restrict__ staging) {
    int i = blockIdx.x * 256 + threadIdx.x;
    int s = blockIdx.x & 7;                 // tracks round-robin block->XCD mapping
    if (i < N_EDGES) {
        int r = erow[i];
        int b = r >> 8;
        int pos = atomicAdd(&fill[(s * NBUCK + b) * 16], 1);
        if (pos < SEGCAP) {
            int2 e;
            e.x = (ecol[i] << 8) | (r & 255);   // col:17b << 8 | row_local:8b
            e.y = __float_as_int(eval[i]);
            staging[(size_t)(b * NSEG + s) * SEGCAP + pos] = e;
        }
    }
}

// ---------- CSR build: prefix over bucket totals ----------
__global__ void bucket_scan(const int* __restrict__ fill, int* __restrict__ bucket_base,
                            int* __restrict__ row_ptr) {
    __shared__ int sdat[512];
    int tid = threadIdx.x;
    int c = 0;
    if (tid < NBUCK) {
        #pragma unroll
        for (int s = 0; s < NSEG; s++) c += fill[(s * NBUCK + tid) * 16];
    }
    sdat[tid] = c;
    __syncthreads();
    for (int off = 1; off < 512; off <<= 1) {
        int t = (tid >= off) ? sdat[tid - off] : 0;
        __syncthreads();
        sdat[tid] += t;
        __syncthreads();
    }
    if (tid < NBUCK) bucket_base[tid] = sdat[tid] - c;   // exclusive
    if (tid == 0) row_ptr[N_NODES] = sdat[511];          // == N_EDGES
}

// ---------- CSR build, phase 2: per-bucket compaction + row_ptr ----------
__global__ __launch_bounds__(256) void phase2_build(
        const int2* __restrict__ staging, const int* __restrict__ fill,
        const int* __restrict__ bucket_base, int* __restrict__ row_ptr,
        int2* __restrict__ edges_s) {
    __shared__ int lhist[256];
    __shared__ int lscan[256];
    __shared__ int lfill[256];
    __shared__ int sseg[NSEG];
    int b = blockIdx.x, tid = threadIdx.x;
    lhist[tid] = 0;
    if (tid < NSEG) sseg[tid] = fill[(tid * NBUCK + b) * 16];
    __syncthreads();
    // pass 1: local row histogram
    for (int s = 0; s < NSEG; s++) {
        int c = sseg[s];
        const int2* seg = staging + (size_t)(b * NSEG + s) * SEGCAP;
        for (int j = tid; j < c; j += 256) atomicAdd(&lhist[seg[j].x & 255], 1);
    }
    __syncthreads();
    int v = lhist[tid];
    lscan[tid] = v;
    __syncthreads();
    for (int off = 1; off < 256; off <<= 1) {
        int t = (tid >= off) ? lscan[tid - off] : 0;
        __syncthreads();
        lscan[tid] += t;
        __syncthreads();
    }
    int base_b = bucket_base[b];
    int excl = base_b + (lscan[tid] - v);
    int grow = b * 256 + tid;
    if (grow < N_NODES) row_ptr[grow] = excl;
    lfill[tid] = excl;
    __syncthreads();
    // pass 2: compact into dense CSR (col, val) pairs
    for (int s = 0; s < NSEG; s++) {
        int c = sseg[s];
        const int2* seg = staging + (size_t)(b * NSEG + s) * SEGCAP;
        for (int j = tid; j < c; j += 256) {
            int2 e = seg[j];
            int rl = e.x & 255;
            int pos = atomicAdd(&lfill[rl], 1);
            edges_s[pos] = make_int2((int)(((unsigned)e.x) >> 8), e.y);
        }
    }
}

// ---------- gating: softmax64 -> top16 -> MLP -> softmax6 (+ bf16 copy of x) ----------
#define GNODES 32   // nodes per block (4 waves x 8 iterations)
__global__ __launch_bounds__(256) void gating_kernel(
        const float* __restrict__ x,  const float* __restrict__ W1,
        const float* __restrict__ b1, const float* __restrict__ W2,
        const float* __restrict__ b2, float* __restrict__ weight,
        float* __restrict__ out_acc, unsigned short* __restrict__ xbf) {
    __shared__ float sW1t[TOPK * NHID];   // transposed: [k][j]
    __shared__ float sb1[NHID];
    __shared__ float sW2[DEG * NHID];
    __shared__ float sb2[DEG];
    int tid = threadIdx.x;
    for (int idx = tid; idx < NHID * TOPK; idx += 256) {
        int k = idx / NHID, j = idx - k * NHID;
        sW1t[idx] = W1[j * TOPK + k];
    }
    for (int i = tid; i < NHID; i += 256) sb1[i] = b1[i];
    for (int i = tid; i < DEG * NHID; i += 256) sW2[i] = W2[i];
    if (tid < DEG) sb2[tid] = b2[tid];
    __syncthreads();

    int wave = tid >> 6;
    int lane = tid & 63;

    for (int it = 0; it < GNODES / 4; it++) {
        int node = blockIdx.x * GNODES + it * 4 + wave;
        if (node >= N_NODES) continue;

        float v = x[node * NCLASS + lane];
        xbf[node * NCLASS + lane] = f2bf(v);

        float m = wave_max(v);
        float e = __expf(v - m);
        float s = wave_sum(e);
        float p = e / s;

        // top-16 descending
        float tk[TOPK];
        float cur = p;
        #pragma unroll
        for (int k = 0; k < TOPK; k++) {
            float mk = wave_max(cur);
            tk[k] = mk;
            unsigned long long mask = __ballot(cur == mk);
            int first = __ffsll(mask) - 1;
            if (lane == first) cur = -1.0f;
        }

        float h0 = sb1[lane], h1 = sb1[lane + 64];
        #pragma unroll
        for (int k = 0; k < TOPK; k++) {
            h0 += tk[k] * sW1t[k * NHID + lane];
            h1 += tk[k] * sW1t[k * NHID + lane + 64];
        }
        h0 = (h0 > 0.f) ? h0 : 0.1f * h0;
        h1 = (h1 > 0.f) ? h1 : 0.1f * h1;

        float w[DEG];
        float wm = -1e30f;
        #pragma unroll
        for (int d = 0; d < DEG; d++) {
            float part = h0 * sW2[d * NHID + lane] + h1 * sW2[d * NHID + lane + 64];
            w[d] = wave_sum(part) + sb2[d];
            wm = fmaxf(wm, w[d]);
        }
        float wsum = 0.f;
        #pragma unroll
        for (int d = 0; d < DEG; d++) { w[d] = __expf(w[d] - wm); wsum += w[d]; }
        float inv = 1.0f / wsum;

        if (lane < DEG) weight[node * DEG + lane] = w[lane] * inv;
        out_acc[node * NCLASS + lane] = w[0] * inv * v;
    }
}

// ---------- SPMM hop: wave per row, 2 edges/iter, ushort2 channel pairs ----------
__global__ __launch_bounds__(256) void spmm_kernel(
        const unsigned short* __restrict__ src, unsigned short* __restrict__ dst,
        const int* __restrict__ row_ptr, const int2* __restrict__ edges_s,
        const float* __restrict__ weight,
        float* __restrict__ out_acc, float* __restrict__ final_out,
        int hop, int is_last) {
    int wave = threadIdx.x >> 6;
    int lane = threadIdx.x & 63;
    int node = blockIdx.x * 4 + wave;
    if (node >= N_NODES) return;

    int half  = lane >> 5;     // 0: even-index edges, 1: odd-index edges
    int laneh = lane & 31;     // channel-pair index (channels 2*laneh, 2*laneh+1)
    const ushort2* src2 = (const ushort2*)src;

    int start = row_ptr[node], end = row_ptr[node + 1];
    float acc0 = 0.f, acc1 = 0.f;
    for (int base = start; base < end; base += 64) {
        int e = base + lane;
        int cl = 0; float vl = 0.f;
        if (e < end) {
            int2 pe = edges_s[e];
            cl = pe.x; vl = __int_as_float(pe.y);
        }
        int cnt = min(64, end - base);
        for (int jj = 0; jj < cnt; jj += 2) {
            int   c0 = __shfl(cl, jj);
            float v0 = __shfl(vl, jj);
            int   j1 = (jj + 1 < cnt) ? jj + 1 : jj;
            int   c1 = __shfl(cl, j1);
            float v1 = (jj + 1 < cnt) ? __shfl(vl, j1) : 0.f;
            int   col = half ? c1 : c0;
            float val = half ? v1 : v0;
            ushort2 pq = src2[col * 32 + laneh];
            acc0 += val * bf2f(pq.x);
            acc1 += val * bf2f(pq.y);
        }
    }
    // combine even/odd halves: after this all 64 lanes hold channel-pair sums
    acc0 += __shfl_xor(acc0, 32);
    acc1 += __shfl_xor(acc1, 32);

    float w = weight[node * DEG + hop];
    if (!is_last) {
        if (half == 0) {
            ushort2 o; o.x = f2bf(acc0); o.y = f2bf(acc1);
            ((ushort2*)dst)[node * 32 + laneh] = o;
            float2* oap = (float2*)&out_acc[node * NCLASS + laneh * 2];
            float2 prev = *oap;
            prev.x += w * acc0; prev.y += w * acc1;
            *oap = prev;
        }
    } else {
        float v0 = out_acc[node * NCLASS + laneh * 2]     + w * acc0;
        float v1 = out_acc[node * NCLASS + laneh * 2 + 1] + w * acc1;
        float m = fmaxf(v0, v1);
        #pragma unroll
        for (int off = 1; off < 32; off <<= 1) m = fmaxf(m, __shfl_xor(m, off));
        float e0 = __expf(v0 - m), e1 = __expf(v1 - m);
        float ssum = e0 + e1;
        #pragma unroll
        for (int off = 1; off < 32; off <<= 1) ssum += __shfl_xor(ssum, off);
        float ls = __logf(ssum);
        if (half == 0) {
            float2 o; o.x = v0 - m - ls; o.y = v1 - m - ls;
            *(float2*)&final_out[node * NCLASS + laneh * 2] = o;
        }
    }
}

extern "C" void kernel_launch(void* const* d_in, const int* in_sizes, int n_in,
                              void* d_out, int out_size, void* d_ws, size_t ws_size,
                              hipStream_t stream) {
    const float* x    = (const float*)d_in[0];
    const int*   erow = (const int*)  d_in[1];
    const int*   ecol = (const int*)  d_in[2];
    const float* eval = (const float*)d_in[3];
    const float* W1   = (const float*)d_in[4];
    const float* b1   = (const float*)d_in[5];
    const float* W2   = (const float*)d_in[6];
    const float* b2   = (const float*)d_in[7];
    float* out = (float*)d_out;   // also the hop-accumulation buffer

    char* ws = (char*)d_ws;
    size_t off = 0;
    auto alloc = [&](size_t bytes) -> void* {
        void* p = ws + off;
        off = (off + bytes + 255) & ~(size_t)255;
        return p;
    };
    // Region A: staging (32.03 MB) is dead before gating runs; xbf/cur0/cur1
    // (38.4 MB) reuse the same space. Stream ordering guarantees safety.
    char* regionA = (char*)alloc((size_t)N_NODES * NCLASS * 2 * 3);   // 38.4 MB
    int2* staging = (int2*)regionA;
    unsigned short* xbf  = (unsigned short*)regionA;
    unsigned short* cur0 = (unsigned short*)(regionA + (size_t)N_NODES * NCLASS * 2);
    unsigned short* cur1 = (unsigned short*)(regionA + (size_t)N_NODES * NCLASS * 4);

    int2*  edges_s     = (int2*)alloc((size_t)N_EDGES * 8);
    int*   row_ptr     = (int*) alloc((size_t)(N_NODES + 1) * 4);
    int*   fill        = (int*) alloc((size_t)NSEG * NBUCK * 16 * 4);   // 64B-padded counters
    int*   bucket_base = (int*) alloc((size_t)NBUCK * 4);
    float* weight      = (float*)alloc((size_t)N_NODES * DEG * 4);

    const int EB = (N_EDGES + 255) / 256;          // 12500
    const int WB = (N_NODES + 3) / 4;              // 25000 (4 waves/block)
    const int GB = (N_NODES + GNODES - 1) / GNODES; // 3125

    // CSR build: bucket scatter -> bucket prefix -> per-bucket compaction
    hipMemsetAsync(fill, 0, (size_t)NSEG * NBUCK * 16 * 4, stream);
    phase1_bucket<<<EB, 256, 0, stream>>>(erow, ecol, eval, fill, staging);
    bucket_scan<<<1, 512, 0, stream>>>(fill, bucket_base, row_ptr);
    phase2_build<<<NBUCK, 256, 0, stream>>>(staging, fill, bucket_base, row_ptr, edges_s);

    // gating: weights + out = w0 * x, and bf16 copy of x (overwrites staging)
    gating_kernel<<<GB, 256, 0, stream>>>(x, W1, b1, W2, b2, weight, out, xbf);

    // 5 hops, out accumulated in d_out; last hop fuses log_softmax
    spmm_kernel<<<WB, 256, 0, stream>>>(xbf,  cur0, row_ptr, edges_s, weight, out, out, 1, 0);
    spmm_kernel<<<WB, 256, 0, stream>>>(cur0, cur1, row_ptr, edges_s, weight, out, out, 2, 0);
    spmm_kernel<<<WB, 256, 0, stream>>>(cur1, cur0, row_ptr, edges_s, weight, out, out, 3, 0);
    spmm_kernel<<<WB, 256, 0, stream>>>(cur0, cur1, row_ptr, edges_s, weight, out, out, 4, 0);
    spmm_kernel<<<WB, 256, 0, stream>>>(cur1, cur0, row_ptr, edges_s, weight, out, out, 5, 1);
}

// Round 4
// 822.567 us; speedup vs baseline: 1.9633x; 1.2696x over previous
//
#include <hip/hip_runtime.h>
#include <math.h>

#define N_NODES 100000
#define N_EDGES 3200000
#define NCLASS  64
#define TOPK    16
#define NHID    128
#define DEG     6

#define NBUCK   391          // ceil(100000/256) buckets of 256 rows
#define NSEG    8            // per-XCD segments per bucket
#define SEGCAP  1280         // capacity per (bucket,segment); mean 1024, sigma 32

// ---------- bf16 helpers ----------
__device__ __forceinline__ float bf2f(unsigned short u) {
    return __uint_as_float(((unsigned)u) << 16);
}
__device__ __forceinline__ unsigned short f2bf(float f) {
    unsigned u = __float_as_uint(f);
    u = (u + 0x7FFFu + ((u >> 16) & 1u)) >> 16;   // round-to-nearest-even
    return (unsigned short)u;
}

// ---------- wave helpers (wave64) ----------
__device__ __forceinline__ float wave_max(float v) {
    #pragma unroll
    for (int off = 1; off < 64; off <<= 1) v = fmaxf(v, __shfl_xor(v, off));
    return v;
}
__device__ __forceinline__ float wave_sum(float v) {
    #pragma unroll
    for (int off = 1; off < 64; off <<= 1) v += __shfl_xor(v, off);
    return v;
}

// ---------- CSR build, phase 1: bucket scatter (XCD-segmented frontiers) ----------
__global__ void phase1_bucket(const int* __restrict__ erow, const int* __restrict__ ecol,
                              const float* __restrict__ eval, int* __restrict__ fill,
                              int2* __restrict__ staging) {
    int i = blockIdx.x * 256 + threadIdx.x;
    int s = blockIdx.x & 7;                 // tracks round-robin block->XCD mapping
    if (i < N_EDGES) {
        int r = erow[i];
        int b = r >> 8;
        int pos = atomicAdd(&fill[(s * NBUCK + b) * 16], 1);
        if (pos < SEGCAP) {
            int2 e;
            e.x = (ecol[i] << 8) | (r & 255);   // col:17b << 8 | row_local:8b
            e.y = __float_as_int(eval[i]);
            staging[(size_t)(b * NSEG + s) * SEGCAP + pos] = e;
        }
    }
}

// ---------- CSR build: prefix over bucket totals ----------
__global__ void bucket_scan(const int* __restrict__ fill, int* __restrict__ bucket_base,
                            int* __restrict__ row_ptr) {
    __shared__ int sdat[512];
    int tid = threadIdx.x;
    int c = 0;
    if (tid < NBUCK) {
        #pragma unroll
        for (int s = 0; s < NSEG; s++) c += fill[(s * NBUCK + tid) * 16];
    }
    sdat[tid] = c;
    __syncthreads();
    for (int off = 1; off < 512; off <<= 1) {
        int t = (tid >= off) ? sdat[tid - off] : 0;
        __syncthreads();
        sdat[tid] += t;
        __syncthreads();
    }
    if (tid < NBUCK) bucket_base[tid] = sdat[tid] - c;   // exclusive
    if (tid == 0) row_ptr[N_NODES] = sdat[511];          // == N_EDGES
}

// ---------- CSR build, phase 2: per-bucket compaction + row_ptr ----------
__global__ __launch_bounds__(256) void phase2_build(
        const int2* __restrict__ staging, const int* __restrict__ fill,
        const int* __restrict__ bucket_base, int* __restrict__ row_ptr,
        int2* __restrict__ edges_s) {
    __shared__ int lhist[256];
    __shared__ int lscan[256];
    __shared__ int lfill[256];
    __shared__ int sseg[NSEG];
    int b = blockIdx.x, tid = threadIdx.x;
    lhist[tid] = 0;
    if (tid < NSEG) sseg[tid] = fill[(tid * NBUCK + b) * 16];
    __syncthreads();
    for (int s = 0; s < NSEG; s++) {
        int c = sseg[s];
        const int2* seg = staging + (size_t)(b * NSEG + s) * SEGCAP;
        for (int j = tid; j < c; j += 256) atomicAdd(&lhist[seg[j].x & 255], 1);
    }
    __syncthreads();
    int v = lhist[tid];
    lscan[tid] = v;
    __syncthreads();
    for (int off = 1; off < 256; off <<= 1) {
        int t = (tid >= off) ? lscan[tid - off] : 0;
        __syncthreads();
        lscan[tid] += t;
        __syncthreads();
    }
    int base_b = bucket_base[b];
    int excl = base_b + (lscan[tid] - v);
    int grow = b * 256 + tid;
    if (grow < N_NODES) row_ptr[grow] = excl;
    lfill[tid] = excl;
    __syncthreads();
    for (int s = 0; s < NSEG; s++) {
        int c = sseg[s];
        const int2* seg = staging + (size_t)(b * NSEG + s) * SEGCAP;
        for (int j = tid; j < c; j += 256) {
            int2 e = seg[j];
            int rl = e.x & 255;
            int pos = atomicAdd(&lfill[rl], 1);
            edges_s[pos] = make_int2((int)(((unsigned)e.x) >> 8), e.y);
        }
    }
}

// ---------- gating: bitonic sort64 -> top16 softmax -> MLP -> softmax6 ----------
#define GNODES 32   // nodes per block (4 waves x 8 iterations)
__global__ __launch_bounds__(256) void gating_kernel(
        const float* __restrict__ x,  const float* __restrict__ W1,
        const float* __restrict__ b1, const float* __restrict__ W2,
        const float* __restrict__ b2, float* __restrict__ weight,
        float* __restrict__ out_acc, unsigned short* __restrict__ xbf) {
    __shared__ float sW1t[TOPK * NHID];   // transposed: [k][j]
    __shared__ float sb1[NHID];
    __shared__ float sW2[DEG * NHID];
    __shared__ float sb2[DEG];
    int tid = threadIdx.x;
    for (int idx = tid; idx < NHID * TOPK; idx += 256) {
        int k = idx / NHID, j = idx - k * NHID;
        sW1t[idx] = W1[j * TOPK + k];
    }
    for (int i = tid; i < NHID; i += 256) sb1[i] = b1[i];
    for (int i = tid; i < DEG * NHID; i += 256) sW2[i] = W2[i];
    if (tid < DEG) sb2[tid] = b2[tid];
    __syncthreads();

    int wave = tid >> 6;
    int lane = tid & 63;

    for (int it = 0; it < GNODES / 4; it++) {
        int node = blockIdx.x * GNODES + it * 4 + wave;
        if (node >= N_NODES) continue;

        float xv = x[node * NCLASS + lane];
        xbf[node * NCLASS + lane] = f2bf(xv);

        // full ascending bitonic sort of x across the wave (21 steps).
        // softmax is monotonic, so top-16 of p == softmax of top-16 of x.
        float v = xv;
        #pragma unroll
        for (int k = 2; k <= 64; k <<= 1) {
            #pragma unroll
            for (int j = k >> 1; j > 0; j >>= 1) {
                float o = __shfl_xor(v, j);
                bool keep_small = (((lane & j) == 0) == ((lane & k) == 0));
                v = keep_small ? fminf(v, o) : fmaxf(v, o);
            }
        }
        float m = __shfl(v, 63);                 // global max
        float e = __expf(v - m);
        float s = wave_sum(e);                   // softmax denominator
        float inv_s = 1.0f / s;

        // layer 1: lane computes h[lane] and h[lane+64]; top-k broadcast inline
        float h0 = sb1[lane], h1 = sb1[lane + 64];
        #pragma unroll
        for (int k = 0; k < TOPK; k++) {
            float sv = __shfl(v, 63 - k);        // k-th largest logit
            float tk = __expf(sv - m) * inv_s;   // k-th largest prob
            h0 += tk * sW1t[k * NHID + lane];
            h1 += tk * sW1t[k * NHID + lane + 64];
        }
        h0 = (h0 > 0.f) ? h0 : 0.1f * h0;
        h1 = (h1 > 0.f) ? h1 : 0.1f * h1;

        float w[DEG];
        float wm = -1e30f;
        #pragma unroll
        for (int d = 0; d < DEG; d++) {
            float part = h0 * sW2[d * NHID + lane] + h1 * sW2[d * NHID + lane + 64];
            w[d] = wave_sum(part) + sb2[d];
            wm = fmaxf(wm, w[d]);
        }
        float wsum = 0.f;
        #pragma unroll
        for (int d = 0; d < DEG; d++) { w[d] = __expf(w[d] - wm); wsum += w[d]; }
        float inv = 1.0f / wsum;

        if (lane < DEG) weight[node * DEG + lane] = w[lane] * inv;
        out_acc[node * NCLASS + lane] = w[0] * inv * xv;
    }
}

// ---------- SPMM hop: wave per row, lane = channel, scalar edge stream ----------
__global__ __launch_bounds__(256) void spmm_kernel(
        const unsigned short* __restrict__ src, unsigned short* __restrict__ dst,
        const int* __restrict__ row_ptr, const int2* __restrict__ edges_s,
        const float* __restrict__ weight,
        float* __restrict__ out_acc, float* __restrict__ final_out,
        int hop, int is_last) {
    int wave = threadIdx.x >> 6;
    int lane = threadIdx.x & 63;
    int node = blockIdx.x * 4 + wave;
    if (node >= N_NODES) return;

    int start = __builtin_amdgcn_readfirstlane(row_ptr[node]);
    int end   = __builtin_amdgcn_readfirstlane(row_ptr[node + 1]);

    float acc = 0.f;
    int e = start;
    // 4-edge groups: 4 independent gathers in flight; edge stream is
    // wave-uniform (readfirstlane) so (col,val) ride in SGPRs.
    for (; e + 4 <= end; e += 4) {
        int2 p0 = edges_s[e];
        int2 p1 = edges_s[e + 1];
        int2 p2 = edges_s[e + 2];
        int2 p3 = edges_s[e + 3];
        int c0 = __builtin_amdgcn_readfirstlane(p0.x);
        int c1 = __builtin_amdgcn_readfirstlane(p1.x);
        int c2 = __builtin_amdgcn_readfirstlane(p2.x);
        int c3 = __builtin_amdgcn_readfirstlane(p3.x);
        float v0 = __int_as_float(__builtin_amdgcn_readfirstlane(p0.y));
        float v1 = __int_as_float(__builtin_amdgcn_readfirstlane(p1.y));
        float v2 = __int_as_float(__builtin_amdgcn_readfirstlane(p2.y));
        float v3 = __int_as_float(__builtin_amdgcn_readfirstlane(p3.y));
        float f0 = bf2f(src[c0 * NCLASS + lane]);
        float f1 = bf2f(src[c1 * NCLASS + lane]);
        float f2 = bf2f(src[c2 * NCLASS + lane]);
        float f3 = bf2f(src[c3 * NCLASS + lane]);
        acc += v0 * f0;
        acc += v1 * f1;
        acc += v2 * f2;
        acc += v3 * f3;
    }
    for (; e < end; e++) {
        int2 p0 = edges_s[e];
        int   c0 = __builtin_amdgcn_readfirstlane(p0.x);
        float v0 = __int_as_float(__builtin_amdgcn_readfirstlane(p0.y));
        acc += v0 * bf2f(src[c0 * NCLASS + lane]);
    }

    float w = weight[node * DEG + hop];
    if (!is_last) {
        dst[node * NCLASS + lane] = f2bf(acc);
        out_acc[node * NCLASS + lane] += w * acc;
    } else {
        float v = out_acc[node * NCLASS + lane] + w * acc;
        float m = wave_max(v);
        float e2 = __expf(v - m);
        float s = wave_sum(e2);
        final_out[node * NCLASS + lane] = v - m - __logf(s);
    }
}

extern "C" void kernel_launch(void* const* d_in, const int* in_sizes, int n_in,
                              void* d_out, int out_size, void* d_ws, size_t ws_size,
                              hipStream_t stream) {
    const float* x    = (const float*)d_in[0];
    const int*   erow = (const int*)  d_in[1];
    const int*   ecol = (const int*)  d_in[2];
    const float* eval = (const float*)d_in[3];
    const float* W1   = (const float*)d_in[4];
    const float* b1   = (const float*)d_in[5];
    const float* W2   = (const float*)d_in[6];
    const float* b2   = (const float*)d_in[7];
    float* out = (float*)d_out;   // also the hop-accumulation buffer

    char* ws = (char*)d_ws;
    size_t off = 0;
    auto alloc = [&](size_t bytes) -> void* {
        void* p = ws + off;
        off = (off + bytes + 255) & ~(size_t)255;
        return p;
    };
    // Region A: staging (32.03 MB) is dead before gating runs; xbf/cur0/cur1
    // (38.4 MB) reuse the same space. Stream ordering guarantees safety.
    char* regionA = (char*)alloc((size_t)N_NODES * NCLASS * 2 * 3);   // 38.4 MB
    int2* staging = (int2*)regionA;
    unsigned short* xbf  = (unsigned short*)regionA;
    unsigned short* cur0 = (unsigned short*)(regionA + (size_t)N_NODES * NCLASS * 2);
    unsigned short* cur1 = (unsigned short*)(regionA + (size_t)N_NODES * NCLASS * 4);

    int2*  edges_s     = (int2*)alloc((size_t)N_EDGES * 8);
    int*   row_ptr     = (int*) alloc((size_t)(N_NODES + 1) * 4);
    int*   fill        = (int*) alloc((size_t)NSEG * NBUCK * 16 * 4);   // 64B-padded counters
    int*   bucket_base = (int*) alloc((size_t)NBUCK * 4);
    float* weight      = (float*)alloc((size_t)N_NODES * DEG * 4);

    const int EB = (N_EDGES + 255) / 256;          // 12500
    const int WB = (N_NODES + 3) / 4;              // 25000 (4 waves/block)
    const int GB = (N_NODES + GNODES - 1) / GNODES; // 3125

    // CSR build: bucket scatter -> bucket prefix -> per-bucket compaction
    hipMemsetAsync(fill, 0, (size_t)NSEG * NBUCK * 16 * 4, stream);
    phase1_bucket<<<EB, 256, 0, stream>>>(erow, ecol, eval, fill, staging);
    bucket_scan<<<1, 512, 0, stream>>>(fill, bucket_base, row_ptr);
    phase2_build<<<NBUCK, 256, 0, stream>>>(staging, fill, bucket_base, row_ptr, edges_s);

    // gating: weights + out = w0 * x, and bf16 copy of x (overwrites staging)
    gating_kernel<<<GB, 256, 0, stream>>>(x, W1, b1, W2, b2, weight, out, xbf);

    // 5 hops, out accumulated in d_out; last hop fuses log_softmax
    spmm_kernel<<<WB, 256, 0, stream>>>(xbf,  cur0, row_ptr, edges_s, weight, out, out, 1, 0);
    spmm_kernel<<<WB, 256, 0, stream>>>(cur0, cur1, row_ptr, edges_s, weight, out, out, 2, 0);
    spmm_kernel<<<WB, 256, 0, stream>>>(cur1, cur0, row_ptr, edges_s, weight, out, out, 3, 0);
    spmm_kernel<<<WB, 256, 0, stream>>>(cur0, cur1, row_ptr, edges_s, weight, out, out, 4, 0);
    spmm_kernel<<<WB, 256, 0, stream>>>(cur1, cur0, row_ptr, edges_s, weight, out, out, 5, 1);
}

// Round 5
// 775.062 us; speedup vs baseline: 2.0836x; 1.0613x over previous
//
#include <hip/hip_runtime.h>
#include <math.h>

#define N_NODES 100000
#define N_EDGES 3200000
#define NCLASS  64
#define TOPK    16
#define NHID    128
#define DEG     6

#define NBUCK   391          // ceil(100000/256) buckets of 256 rows
#define NSEG    8            // per-XCD segments per bucket (real XCC_ID)
#define SEGCAP  1408         // capacity per (bucket,segment); mean 1024

// ---------- bf16 helpers ----------
__device__ __forceinline__ float bf2f(unsigned short u) {
    return __uint_as_float(((unsigned)u) << 16);
}
__device__ __forceinline__ unsigned short f2bf(float f) {
    unsigned u = __float_as_uint(f);
    u = (u + 0x7FFFu + ((u >> 16) & 1u)) >> 16;   // round-to-nearest-even
    return (unsigned short)u;
}

// ---------- wave helpers (wave64) ----------
__device__ __forceinline__ float wave_max(float v) {
    #pragma unroll
    for (int off = 1; off < 64; off <<= 1) v = fmaxf(v, __shfl_xor(v, off));
    return v;
}
__device__ __forceinline__ float wave_sum(float v) {
    #pragma unroll
    for (int off = 1; off < 64; off <<= 1) v += __shfl_xor(v, off);
    return v;
}

// ---------- CSR build, phase 1: bucket scatter segmented by REAL XCD id ----------
// All stores/atomics for segment s come from XCD s only -> its L2 merges
// the 8x8B stores per line into one full-line writeback.
__global__ void phase1_bucket(const int* __restrict__ erow, const int* __restrict__ ecol,
                              const float* __restrict__ eval, int* __restrict__ fill,
                              int2* __restrict__ staging) {
    unsigned xcc;
    asm("s_getreg_b32 %0, hwreg(HW_REG_XCC_ID)" : "=s"(xcc));
    int s = (int)(xcc & 7u);
    int i = blockIdx.x * 256 + threadIdx.x;
    if (i < N_EDGES) {
        int r = __builtin_nontemporal_load(&erow[i]);
        int c = __builtin_nontemporal_load(&ecol[i]);
        float w = __builtin_nontemporal_load(&eval[i]);
        int b = r >> 8;
        int pos = atomicAdd(&fill[(s * NBUCK + b) * 16], 1);
        if (pos < SEGCAP) {
            int2 e;
            e.x = (c << 8) | (r & 255);   // col:17b << 8 | row_local:8b
            e.y = __float_as_int(w);
            staging[((size_t)b * NSEG + s) * SEGCAP + pos] = e;
        }
    }
}

// ---------- CSR build: prefix over bucket totals ----------
__global__ void bucket_scan(const int* __restrict__ fill, int* __restrict__ bucket_base,
                            int* __restrict__ row_ptr) {
    __shared__ int sdat[512];
    int tid = threadIdx.x;
    int c = 0;
    if (tid < NBUCK) {
        #pragma unroll
        for (int s = 0; s < NSEG; s++) c += min(fill[(s * NBUCK + tid) * 16], SEGCAP);
    }
    sdat[tid] = c;
    __syncthreads();
    for (int off = 1; off < 512; off <<= 1) {
        int t = (tid >= off) ? sdat[tid - off] : 0;
        __syncthreads();
        sdat[tid] += t;
        __syncthreads();
    }
    if (tid < NBUCK) bucket_base[tid] = sdat[tid] - c;   // exclusive
    if (tid == 0) row_ptr[N_NODES] = sdat[511];          // == N_EDGES
}

// ---------- CSR build, phase 2: per-bucket compaction + row_ptr ----------
__global__ __launch_bounds__(256) void phase2_build(
        const int2* __restrict__ staging, const int* __restrict__ fill,
        const int* __restrict__ bucket_base, int* __restrict__ row_ptr,
        int2* __restrict__ edges_s) {
    __shared__ int lhist[256];
    __shared__ int lscan[256];
    __shared__ int lfill[256];
    __shared__ int sseg[NSEG];
    int b = blockIdx.x, tid = threadIdx.x;
    lhist[tid] = 0;
    if (tid < NSEG) sseg[tid] = min(fill[(tid * NBUCK + b) * 16], SEGCAP);
    __syncthreads();
    for (int s = 0; s < NSEG; s++) {
        int c = sseg[s];
        const int2* seg = staging + ((size_t)b * NSEG + s) * SEGCAP;
        for (int j = tid; j < c; j += 256) atomicAdd(&lhist[seg[j].x & 255], 1);
    }
    __syncthreads();
    int v = lhist[tid];
    lscan[tid] = v;
    __syncthreads();
    for (int off = 1; off < 256; off <<= 1) {
        int t = (tid >= off) ? lscan[tid - off] : 0;
        __syncthreads();
        lscan[tid] += t;
        __syncthreads();
    }
    int base_b = bucket_base[b];
    int excl = base_b + (lscan[tid] - v);
    int grow = b * 256 + tid;
    if (grow < N_NODES) row_ptr[grow] = excl;
    lfill[tid] = excl;
    __syncthreads();
    for (int s = 0; s < NSEG; s++) {
        int c = sseg[s];
        const int2* seg = staging + ((size_t)b * NSEG + s) * SEGCAP;
        for (int j = tid; j < c; j += 256) {
            int2 e = seg[j];
            int rl = e.x & 255;
            int pos = atomicAdd(&lfill[rl], 1);
            edges_s[pos] = make_int2((int)(((unsigned)e.x) >> 8), e.y);
        }
    }
}

// ---------- gating: bitonic sort64 -> top16 softmax -> MLP -> softmax6 ----------
#define GNODES 32   // nodes per block (4 waves x 8 iterations)
__global__ __launch_bounds__(256) void gating_kernel(
        const float* __restrict__ x,  const float* __restrict__ W1,
        const float* __restrict__ b1, const float* __restrict__ W2,
        const float* __restrict__ b2, float* __restrict__ weight,
        float* __restrict__ out_acc, unsigned short* __restrict__ xbf) {
    __shared__ float sW1t[TOPK * NHID];   // transposed: [k][j]
    __shared__ float sb1[NHID];
    __shared__ float sW2[DEG * NHID];
    __shared__ float sb2[DEG];
    int tid = threadIdx.x;
    for (int idx = tid; idx < NHID * TOPK; idx += 256) {
        int k = idx / NHID, j = idx - k * NHID;
        sW1t[idx] = W1[j * TOPK + k];
    }
    for (int i = tid; i < NHID; i += 256) sb1[i] = b1[i];
    for (int i = tid; i < DEG * NHID; i += 256) sW2[i] = W2[i];
    if (tid < DEG) sb2[tid] = b2[tid];
    __syncthreads();

    int wave = tid >> 6;
    int lane = tid & 63;

    for (int it = 0; it < GNODES / 4; it++) {
        int node = blockIdx.x * GNODES + it * 4 + wave;
        if (node >= N_NODES) continue;

        float xv = x[node * NCLASS + lane];
        xbf[node * NCLASS + lane] = f2bf(xv);

        // full ascending bitonic sort of x across the wave (21 steps).
        float v = xv;
        #pragma unroll
        for (int k = 2; k <= 64; k <<= 1) {
            #pragma unroll
            for (int j = k >> 1; j > 0; j >>= 1) {
                float o = __shfl_xor(v, j);
                bool keep_small = (((lane & j) == 0) == ((lane & k) == 0));
                v = keep_small ? fminf(v, o) : fmaxf(v, o);
            }
        }
        float m = __shfl(v, 63);                 // global max
        float e = __expf(v - m);
        float s = wave_sum(e);                   // softmax denominator
        float inv_s = 1.0f / s;

        float h0 = sb1[lane], h1 = sb1[lane + 64];
        #pragma unroll
        for (int k = 0; k < TOPK; k++) {
            float sv = __shfl(v, 63 - k);        // k-th largest logit
            float tk = __expf(sv - m) * inv_s;   // k-th largest prob
            h0 += tk * sW1t[k * NHID + lane];
            h1 += tk * sW1t[k * NHID + lane + 64];
        }
        h0 = (h0 > 0.f) ? h0 : 0.1f * h0;
        h1 = (h1 > 0.f) ? h1 : 0.1f * h1;

        float w[DEG];
        float wm = -1e30f;
        #pragma unroll
        for (int d = 0; d < DEG; d++) {
            float part = h0 * sW2[d * NHID + lane] + h1 * sW2[d * NHID + lane + 64];
            w[d] = wave_sum(part) + sb2[d];
            wm = fmaxf(wm, w[d]);
        }
        float wsum = 0.f;
        #pragma unroll
        for (int d = 0; d < DEG; d++) { w[d] = __expf(w[d] - wm); wsum += w[d]; }
        float inv = 1.0f / wsum;

        if (lane < DEG) weight[node * DEG + lane] = w[lane] * inv;
        out_acc[node * NCLASS + lane] = w[0] * inv * xv;
    }
}

// ---------- SPMM hop: wave per row, lane = channel, scalar NT edge stream ----------
__global__ __launch_bounds__(256) void spmm_kernel(
        const unsigned short* __restrict__ src, unsigned short* __restrict__ dst,
        const int* __restrict__ row_ptr, const int2* __restrict__ edges_s,
        const float* __restrict__ weight,
        float* __restrict__ out_acc, float* __restrict__ final_out,
        int hop, int is_last) {
    int wave = threadIdx.x >> 6;
    int lane = threadIdx.x & 63;
    int node = blockIdx.x * 4 + wave;
    if (node >= N_NODES) return;

    int start = __builtin_amdgcn_readfirstlane(row_ptr[node]);
    int end   = __builtin_amdgcn_readfirstlane(row_ptr[node + 1]);

    const long long* edq = (const long long*)edges_s;
    float acc = 0.f;
    int e = start;
    // 8-edge groups: 8 independent gathers in flight; edge stream read once
    // -> nontemporal (don't evict src gather lines from L2).
    for (; e + 8 <= end; e += 8) {
        long long q[8];
        #pragma unroll
        for (int k = 0; k < 8; k++) q[k] = __builtin_nontemporal_load(&edq[e + k]);
        float vv[8], ff[8];
        #pragma unroll
        for (int k = 0; k < 8; k++) {
            int col = __builtin_amdgcn_readfirstlane((int)(unsigned)q[k]);
            vv[k] = __int_as_float(__builtin_amdgcn_readfirstlane((int)(q[k] >> 32)));
            ff[k] = bf2f(src[col * NCLASS + lane]);
        }
        #pragma unroll
        for (int k = 0; k < 8; k++) acc += vv[k] * ff[k];
    }
    for (; e < end; e++) {
        long long q0 = __builtin_nontemporal_load(&edq[e]);
        int   c0 = __builtin_amdgcn_readfirstlane((int)(unsigned)q0);
        float v0 = __int_as_float(__builtin_amdgcn_readfirstlane((int)(q0 >> 32)));
        acc += v0 * bf2f(src[c0 * NCLASS + lane]);
    }

    float w = weight[node * DEG + hop];
    if (!is_last) {
        dst[node * NCLASS + lane] = f2bf(acc);
        out_acc[node * NCLASS + lane] += w * acc;
    } else {
        float v = out_acc[node * NCLASS + lane] + w * acc;
        float m = wave_max(v);
        float e2 = __expf(v - m);
        float s = wave_sum(e2);
        final_out[node * NCLASS + lane] = v - m - __logf(s);
    }
}

extern "C" void kernel_launch(void* const* d_in, const int* in_sizes, int n_in,
                              void* d_out, int out_size, void* d_ws, size_t ws_size,
                              hipStream_t stream) {
    const float* x    = (const float*)d_in[0];
    const int*   erow = (const int*)  d_in[1];
    const int*   ecol = (const int*)  d_in[2];
    const float* eval = (const float*)d_in[3];
    const float* W1   = (const float*)d_in[4];
    const float* b1   = (const float*)d_in[5];
    const float* W2   = (const float*)d_in[6];
    const float* b2   = (const float*)d_in[7];
    float* out = (float*)d_out;   // also the hop-accumulation buffer

    char* ws = (char*)d_ws;
    size_t off = 0;
    auto alloc = [&](size_t bytes) -> void* {
        void* p = ws + off;
        off = (off + bytes + 255) & ~(size_t)255;
        return p;
    };
    // Region A: staging (35.2 MB) is dead before gating runs; xbf/cur0/cur1
    // (38.4 MB) reuse the same space. Stream ordering guarantees safety.
    char* regionA = (char*)alloc((size_t)N_NODES * NCLASS * 2 * 3);   // 38.4 MB
    int2* staging = (int2*)regionA;
    unsigned short* xbf  = (unsigned short*)regionA;
    unsigned short* cur0 = (unsigned short*)(regionA + (size_t)N_NODES * NCLASS * 2);
    unsigned short* cur1 = (unsigned short*)(regionA + (size_t)N_NODES * NCLASS * 4);

    int2*  edges_s     = (int2*)alloc((size_t)N_EDGES * 8);
    int*   row_ptr     = (int*) alloc((size_t)(N_NODES + 1) * 4);
    int*   fill        = (int*) alloc((size_t)NSEG * NBUCK * 16 * 4);   // 64B-padded counters
    int*   bucket_base = (int*) alloc((size_t)NBUCK * 4);
    float* weight      = (float*)alloc((size_t)N_NODES * DEG * 4);

    const int EB = (N_EDGES + 255) / 256;          // 12500
    const int WB = (N_NODES + 3) / 4;              // 25000 (4 waves/block)
    const int GB = (N_NODES + GNODES - 1) / GNODES; // 3125

    // CSR build: XCD-segmented bucket scatter -> bucket prefix -> compaction
    hipMemsetAsync(fill, 0, (size_t)NSEG * NBUCK * 16 * 4, stream);
    phase1_bucket<<<EB, 256, 0, stream>>>(erow, ecol, eval, fill, staging);
    bucket_scan<<<1, 512, 0, stream>>>(fill, bucket_base, row_ptr);
    phase2_build<<<NBUCK, 256, 0, stream>>>(staging, fill, bucket_base, row_ptr, edges_s);

    // gating: weights + out = w0 * x, and bf16 copy of x (overwrites staging)
    gating_kernel<<<GB, 256, 0, stream>>>(x, W1, b1, W2, b2, weight, out, xbf);

    // 5 hops, out accumulated in d_out; last hop fuses log_softmax
    spmm_kernel<<<WB, 256, 0, stream>>>(xbf,  cur0, row_ptr, edges_s, weight, out, out, 1, 0);
    spmm_kernel<<<WB, 256, 0, stream>>>(cur0, cur1, row_ptr, edges_s, weight, out, out, 2, 0);
    spmm_kernel<<<WB, 256, 0, stream>>>(cur1, cur0, row_ptr, edges_s, weight, out, out, 3, 0);
    spmm_kernel<<<WB, 256, 0, stream>>>(cur0, cur1, row_ptr, edges_s, weight, out, out, 4, 0);
    spmm_kernel<<<WB, 256, 0, stream>>>(cur1, cur0, row_ptr, edges_s, weight, out, out, 5, 1);
}